// Round 5
// baseline (294.026 us; speedup 1.0000x reference)
//
#include <hip/hip_runtime.h>
#include <math.h>

// Problem constants (static per reference)
#define B_    256
#define N_    400
#define D_    256
#define EPG_  12800          // N*DEG edges per graph (block-diagonal, contiguous)
#define E_    3276800        // B*EPG
#define NT_   102400         // B*N
#define K_    200            // ceil(0.5*N)
#define NKC_  200            // N-K

// Output flat offsets (float32 elements, in return order).
// O_FDIS..O_FCOM regions are contiguous, so concatenated output row
// r in [0, B*N) lives at out + r*D  (r < B*K => dis, else com).
#define O_FDIS 0
#define O_FCOM 13107200      // + B*K*D
#define O_PERM 26214400      // + B*NKC*D
#define O_PCOM 26265600      // + B*K
#define O_SOFT 26316800      // + B*NKC
#define O_EDIS 26419200      // + NT
#define O_ECOM 29696000      // + E

#define NEG_INF (-3.402823466e38f)

// Native clang vector type: __builtin_nontemporal_store rejects HIP's
// float4 class but accepts ext_vector_type. Same 16-B layout/alignment.
typedef float nfv4 __attribute__((ext_vector_type(4)));

static __device__ __forceinline__ void nt_store4(float4* p, float4 v) {
    nfv4 x; x.x = v.x; x.y = v.y; x.z = v.z; x.w = v.w;
    __builtin_nontemporal_store(x, (nfv4*)p);
}

// ---------------------------------------------------------------------------
// k_h: hraw[n] = dot(feat[n], W). Wave per 4 rows; pure 105 MB stream at HBM
// rate (measured 6.2 TB/s). Also warms L3 with feat for k_gather.
// Grid MUST be NT_/16 blocks.
// ---------------------------------------------------------------------------
__global__ __launch_bounds__(256) void k_h(const float* __restrict__ feat,
                                           const float* __restrict__ W,
                                           float* __restrict__ hraw) {
    const int gw   = (blockIdx.x * 256 + threadIdx.x) >> 6;
    const int lane = threadIdx.x & 63;
    const float4 w4 = ((const float4*)W)[lane];
    const int r0 = gw * 4;
    const float4* fb = (const float4*)feat;
    float4 a0 = fb[(size_t)(r0    ) * 64 + lane];
    float4 a1 = fb[(size_t)(r0 + 1) * 64 + lane];
    float4 a2 = fb[(size_t)(r0 + 2) * 64 + lane];
    float4 a3 = fb[(size_t)(r0 + 3) * 64 + lane];
    float d0 = a0.x*w4.x + a0.y*w4.y + a0.z*w4.z + a0.w*w4.w;
    float d1 = a1.x*w4.x + a1.y*w4.y + a1.z*w4.z + a1.w*w4.w;
    float d2 = a2.x*w4.x + a2.y*w4.y + a2.z*w4.z + a2.w*w4.w;
    float d3 = a3.x*w4.x + a3.y*w4.y + a3.z*w4.z + a3.w*w4.w;
    #pragma unroll
    for (int off = 32; off > 0; off >>= 1) {
        d0 += __shfl_down(d0, off, 64);
        d1 += __shfl_down(d1, off, 64);
        d2 += __shfl_down(d2, off, 64);
        d3 += __shfl_down(d3, off, 64);
    }
    if (lane == 0) {
        hraw[r0    ] = d0;
        hraw[r0 + 1] = d1;
        hraw[r0 + 2] = d2;
        hraw[r0 + 3] = d3;
    }
}

// ---------------------------------------------------------------------------
// k_graph: per-graph LOGIC ONLY (no bulk streams — those run 3x slower here
// than in wide kernels, measured R3/R4). One 1024-thr block per graph:
//  P1: degree histograms (LDS atomics over the graph's 12800 edges, 26 MB
//      total across grid — the only bulk read)
//  P2: hl = hraw * norm_out
//  P3: normed scatter-sum (edges L2-hot)
//  P4: score = scl * norm_in + b
//  P5: rank-select top-k in registers (waves 0-6, shfl broadcast)
//      || wave 15 softmax partial
//  P6: complement positions from ballot masks (O(1)/thread)
// Outputs: score, sel, orow, perm, pcom, (pm,ps). ~3 MB total writes.
// ---------------------------------------------------------------------------
__global__ __launch_bounds__(1024) void k_graph(const int* __restrict__ src,
                                                const int* __restrict__ dst,
                                                const float* __restrict__ hraw,
                                                const float* __restrict__ bp,
                                                float* __restrict__ score,
                                                float* __restrict__ pm,
                                                float* __restrict__ ps,
                                                int* __restrict__ sel,
                                                int* __restrict__ orow,
                                                float* __restrict__ out) {
    __shared__ float hl[N_], scl[N_];
    __shared__ int   ho[N_], hi[N_];
    __shared__ unsigned long long bmask[7];

    const int g = blockIdx.x, tid = threadIdx.x;
    const int nbase = g * N_, ebase = g * EPG_;
    const int wave = tid >> 6, lane = tid & 63;

    // Early-issue the tiny hraw read; completes under the edge pass.
    float hr = 0.0f;
    if (tid < N_) hr = hraw[nbase + tid];

    if (tid < N_) { ho[tid] = 0; hi[tid] = 0; scl[tid] = 0.0f; }
    __syncthreads();

    const int4* s4 = (const int4*)(src + ebase);   // 3200 int4
    const int4* d4 = (const int4*)(dst + ebase);

    // --- P1: degree histograms, all 16 waves
    for (int i = tid; i < EPG_ / 4; i += 1024) {
        int4 s = s4[i]; int4 d = d4[i];
        atomicAdd(&ho[s.x - nbase], 1);
        atomicAdd(&ho[s.y - nbase], 1);
        atomicAdd(&ho[s.z - nbase], 1);
        atomicAdd(&ho[s.w - nbase], 1);
        atomicAdd(&hi[d.x - nbase], 1);
        atomicAdd(&hi[d.y - nbase], 1);
        atomicAdd(&hi[d.z - nbase], 1);
        atomicAdd(&hi[d.w - nbase], 1);
    }
    __syncthreads();

    // --- P2
    if (tid < N_)
        hl[tid] = hr * (1.0f / sqrtf(fmaxf((float)ho[tid], 1.0f)));
    __syncthreads();

    // --- P3: normed scatter-sum (edges L2-hot)
    for (int i = tid; i < EPG_ / 4; i += 1024) {
        int4 s = s4[i]; int4 d = d4[i];
        atomicAdd(&scl[d.x - nbase], hl[s.x - nbase]);
        atomicAdd(&scl[d.y - nbase], hl[s.y - nbase]);
        atomicAdd(&scl[d.z - nbase], hl[s.z - nbase]);
        atomicAdd(&scl[d.w - nbase], hl[s.w - nbase]);
    }
    __syncthreads();

    // --- P4: score
    const float bb = bp[0];
    if (tid < N_) {
        float v = scl[tid] * (1.0f / sqrtf(fmaxf((float)hi[tid], 1.0f))) + bb;
        scl[tid] = v;
        score[nbase + tid] = v;
    }
    __syncthreads();

    // --- P5: rank-select top-k in registers (waves 0-6; 448 lanes).
    // rank_i = #{j : s_j > s_i or (s_j == s_i and j < i)}; selected iff < K,
    // list position == rank (== lax.top_k stable-descending order).
    bool selb = false;
    if (tid < 448) {
        float sreg[7];
        #pragma unroll
        for (int t = 0; t < 7; ++t) {
            const int j = t * 64 + lane;
            sreg[t] = (j < N_) ? scl[j] : NEG_INF;
        }
        const float v = (tid < N_) ? scl[tid] : NEG_INF;
        int rnk = 0;
        #pragma unroll
        for (int t = 0; t < 7; ++t) {
            #pragma unroll
            for (int l2 = 0; l2 < 64; ++l2) {
                const float u = __shfl(sreg[t], l2, 64);
                const int j = t * 64 + l2;
                rnk += ((u > v) || (u == v && j < tid)) ? 1 : 0;
            }
        }
        selb = (tid < N_) && (rnk < K_);
        if (tid < N_) sel[nbase + tid] = selb ? 1 : 0;
        if (selb) {
            orow[nbase + tid] = g * K_ + rnk;               // dis rows: [0, B*K)
            out[O_PERM + g * K_ + rnk] = (float)(nbase + tid);
        }
        unsigned long long bal = __ballot(selb);
        if (lane == 0) bmask[wave] = bal;
    }
    // Wave 15 computes the per-graph softmax partial from scl (read-only).
    if (wave == 15) {
        float m = NEG_INF;
        for (int i = lane; i < N_; i += 64) m = fmaxf(m, scl[i]);
        #pragma unroll
        for (int o = 32; o > 0; o >>= 1) m = fmaxf(m, __shfl_xor(m, o, 64));
        float s = 0.0f;
        for (int i = lane; i < N_; i += 64) s += expf(scl[i] - m);
        #pragma unroll
        for (int o = 32; o > 0; o >>= 1) s += __shfl_xor(s, o, 64);
        if (lane == 0) { pm[g] = m; ps[g] = s; }
    }
    __syncthreads();

    // --- P6: complement positions from ballots: pos = tid - #sel_below
    if (tid < N_ && !selb) {
        int nsel = 0;
        #pragma unroll
        for (int w = 0; w < 7; ++w)
            if (w < wave) nsel += (int)__popcll(bmask[w]);
        nsel += (int)__popcll(bmask[wave] & ((1ull << lane) - 1ull));
        const int pos = tid - nsel;
        orow[nbase + tid] = B_ * K_ + g * NKC_ + pos;       // com rows
        out[O_PCOM + g * NKC_ + pos] = (float)(nbase + tid);
    }
}

// Combine per-graph (max,sumexp) into global (M,S)
__global__ __launch_bounds__(256) void k_soft_comb(const float* pm, const float* ps, float* red2) {
    __shared__ float rm[256], rs[256];
    int tid = threadIdx.x;
    float m = pm[tid];
    rm[tid] = m; __syncthreads();
    for (int o = 128; o > 0; o >>= 1) { if (tid < o) rm[tid] = fmaxf(rm[tid], rm[tid + o]); __syncthreads(); }
    float M = rm[0]; __syncthreads();
    rs[tid] = ps[tid] * expf(m - M); __syncthreads();
    for (int o = 128; o > 0; o >>= 1) { if (tid < o) rs[tid] += rs[tid + o]; __syncthreads(); }
    if (tid == 0) { red2[0] = M; red2[1] = rs[0]; }
}

// Edge masks: wide (3200 blocks). Edges are L3-hot (k_graph just read them),
// sel (0.4 MB) is L2-resident; 52 MB of nt float4 writes.
__global__ __launch_bounds__(256) void k_mask(const int* __restrict__ src,
                                              const int* __restrict__ dst,
                                              const int* __restrict__ sel,
                                              float* __restrict__ out) {
    const int i = blockIdx.x * 256 + threadIdx.x;   // 0 .. E/4-1
    int4 s = ((const int4*)src)[i];
    int4 d = ((const int4*)dst)[i];
    int a0 = sel[s.x], a1 = sel[s.y], a2 = sel[s.z], a3 = sel[s.w];
    int b0 = sel[d.x], b1 = sel[d.y], b2 = sel[d.z], b3 = sel[d.w];
    float4 mdis, mcom;
    mdis.x = (a0 & b0) ? 1.0f : 0.0f;  mcom.x = (a0 | b0) ? 0.0f : 1.0f;
    mdis.y = (a1 & b1) ? 1.0f : 0.0f;  mcom.y = (a1 | b1) ? 0.0f : 1.0f;
    mdis.z = (a2 & b2) ? 1.0f : 0.0f;  mcom.z = (a2 | b2) ? 0.0f : 1.0f;
    mdis.w = (a3 & b3) ? 1.0f : 0.0f;  mcom.w = (a3 | b3) ? 0.0f : 1.0f;
    nt_store4(((float4*)(out + O_EDIS)) + i, mdis);
    nt_store4(((float4*)(out + O_ECOM)) + i, mcom);
}

// Gated gather with LINEAR feature reads (L3-hot from k_h): wave handles 4
// consecutive nodes, writes each row to out + orow[n]*D with nt stores.
// Softmax output fused. Grid MUST be NT_/16 blocks.
__global__ __launch_bounds__(256) void k_gather(const float* __restrict__ feat,
                                                const float* __restrict__ score,
                                                const int* __restrict__ orow,
                                                const float* __restrict__ red2,
                                                float* __restrict__ out) {
    const int gw   = (blockIdx.x * 256 + threadIdx.x) >> 6;
    const int lane = threadIdx.x & 63;
    const int n0 = gw * 4;
    const float4* fb = (const float4*)feat;
    float4 v0 = fb[(size_t)(n0    ) * 64 + lane];
    float4 v1 = fb[(size_t)(n0 + 1) * 64 + lane];
    float4 v2 = fb[(size_t)(n0 + 2) * 64 + lane];
    float4 v3 = fb[(size_t)(n0 + 3) * 64 + lane];
    float s0 = score[n0], s1 = score[n0 + 1], s2 = score[n0 + 2], s3 = score[n0 + 3];
    int   r0 = orow[n0],  r1 = orow[n0 + 1],  r2 = orow[n0 + 2],  r3 = orow[n0 + 3];
    float t0 = tanhf(s0), t1 = tanhf(s1), t2 = tanhf(s2), t3 = tanhf(s3);
    v0.x *= t0; v0.y *= t0; v0.z *= t0; v0.w *= t0;
    v1.x *= t1; v1.y *= t1; v1.z *= t1; v1.w *= t1;
    v2.x *= t2; v2.y *= t2; v2.z *= t2; v2.w *= t2;
    v3.x *= t3; v3.y *= t3; v3.z *= t3; v3.w *= t3;
    nt_store4(((float4*)(out + (size_t)r0 * D_)) + lane, v0);
    nt_store4(((float4*)(out + (size_t)r1 * D_)) + lane, v1);
    nt_store4(((float4*)(out + (size_t)r2 * D_)) + lane, v2);
    nt_store4(((float4*)(out + (size_t)r3 * D_)) + lane, v3);
    if (lane == 0) {
        float M = red2[0], S = red2[1];
        out[O_SOFT + n0    ] = expf(s0 - M) / S;
        out[O_SOFT + n0 + 1] = expf(s1 - M) / S;
        out[O_SOFT + n0 + 2] = expf(s2 - M) / S;
        out[O_SOFT + n0 + 3] = expf(s3 - M) / S;
    }
}

extern "C" void kernel_launch(void* const* d_in, const int* in_sizes, int n_in,
                              void* d_out, int out_size, void* d_ws, size_t ws_size,
                              hipStream_t stream) {
    const float* feat = (const float*)d_in[0];
    const float* W    = (const float*)d_in[1];
    const float* bp   = (const float*)d_in[2];
    const int*   src  = (const int*)d_in[3];
    const int*   dst  = (const int*)d_in[4];
    float* out = (float*)d_out;

    char* ws = (char*)d_ws;
    float* hraw  = (float*)(ws + 0);         // NT_ floats
    float* score = (float*)(ws + 409600);    // NT_ floats
    int*   sel   = (int*)  (ws + 819200);    // NT_ ints
    int*   orow  = (int*)  (ws + 1228800);   // NT_ ints
    float* pm    = (float*)(ws + 1638400);   // B_ floats
    float* ps    = (float*)(ws + 1639424);   // B_ floats
    float* red2  = (float*)(ws + 1640448);   // 2 floats

    k_h        <<<NT_ / 16,    256, 0, stream>>>(feat, W, hraw);            // 6400 blocks
    k_graph    <<<B_,         1024, 0, stream>>>(src, dst, hraw, bp,
                                                 score, pm, ps, sel, orow, out);
    k_soft_comb<<<1,           256, 0, stream>>>(pm, ps, red2);
    k_mask     <<<E_ / 4 / 256, 256, 0, stream>>>(src, dst, sel, out);      // 3200 blocks
    k_gather   <<<NT_ / 16,    256, 0, stream>>>(feat, score, orow, red2, out); // 6400 blocks
}

// Round 6
// 293.777 us; speedup vs baseline: 1.0008x; 1.0008x over previous
//
#include <hip/hip_runtime.h>
#include <math.h>

// Problem constants (static per reference)
#define B_    256
#define N_    400
#define D_    256
#define EPG_  12800          // N*DEG edges per graph (block-diagonal, contiguous)
#define E_    3276800        // B*EPG
#define NT_   102400         // B*N
#define K_    200            // ceil(0.5*N)
#define NKC_  200            // N-K

// Output flat offsets (float32 elements, in return order).
#define O_FDIS 0
#define O_FCOM 13107200      // + B*K*D
#define O_PERM 26214400      // + B*NKC*D
#define O_PCOM 26265600      // + B*K
#define O_SOFT 26316800      // + B*NKC
#define O_EDIS 26419200      // + NT
#define O_ECOM 29696000      // + E

#define NEG_INF (-3.402823466e38f)

// Native clang vector for __builtin_nontemporal_store (rejects HIP float4).
typedef float nfv4 __attribute__((ext_vector_type(4)));
static __device__ __forceinline__ void nt_store4(float4* p, float4 v) {
    nfv4 x; x.x = v.x; x.y = v.y; x.z = v.z; x.w = v.w;
    __builtin_nontemporal_store(x, (nfv4*)p);
}

// ---------------------------------------------------------------------------
// k_h: hraw[n] = dot(feat[n], W). Wave per 4 rows; 105 MB stream @ ~6.2 TB/s
// (measured). Also folds in the zeroing of dego/degi (2*NT ints) so no
// memset dispatch is needed. Grid MUST be NT_/16 blocks.
// ---------------------------------------------------------------------------
__global__ __launch_bounds__(256) void k_h(const float* __restrict__ feat,
                                           const float* __restrict__ W,
                                           float* __restrict__ hraw,
                                           int* __restrict__ degz) {
    const int gid  = blockIdx.x * 256 + threadIdx.x;
    if (gid < 2 * NT_) degz[gid] = 0;               // zero dego||degi
    const int gw   = gid >> 6;
    const int lane = threadIdx.x & 63;
    const float4 w4 = ((const float4*)W)[lane];
    const int r0 = gw * 4;
    const float4* fb = (const float4*)feat;
    float4 a0 = fb[(size_t)(r0    ) * 64 + lane];
    float4 a1 = fb[(size_t)(r0 + 1) * 64 + lane];
    float4 a2 = fb[(size_t)(r0 + 2) * 64 + lane];
    float4 a3 = fb[(size_t)(r0 + 3) * 64 + lane];
    float d0 = a0.x*w4.x + a0.y*w4.y + a0.z*w4.z + a0.w*w4.w;
    float d1 = a1.x*w4.x + a1.y*w4.y + a1.z*w4.z + a1.w*w4.w;
    float d2 = a2.x*w4.x + a2.y*w4.y + a2.z*w4.z + a2.w*w4.w;
    float d3 = a3.x*w4.x + a3.y*w4.y + a3.z*w4.z + a3.w*w4.w;
    #pragma unroll
    for (int off = 32; off > 0; off >>= 1) {
        d0 += __shfl_down(d0, off, 64);
        d1 += __shfl_down(d1, off, 64);
        d2 += __shfl_down(d2, off, 64);
        d3 += __shfl_down(d3, off, 64);
    }
    if (lane == 0) {
        hraw[r0    ] = d0;
        hraw[r0 + 1] = d1;
        hraw[r0 + 2] = d2;
        hraw[r0 + 3] = d3;
    }
}

// ---------------------------------------------------------------------------
// k_deg: WIDE degree histograms. 1024 blocks x 256 thr (4 blocks/graph,
// 4 blocks/CU -> stalls overlap across independent blocks). Per-WAVE private
// LDS histograms kill cross-wave same-address atomic serialization (the
// monolith's killer); merge via global int atomics (4-way contention only).
// Also zeroes agg for k_scat.
// ---------------------------------------------------------------------------
__global__ __launch_bounds__(256) void k_deg(const int* __restrict__ src,
                                             const int* __restrict__ dst,
                                             int* __restrict__ dego,
                                             int* __restrict__ degi,
                                             float* __restrict__ aggz) {
    __shared__ int hp[8][N_];    // [wave*2 + (0=out,1=in)][node], 12.8 KB
    const int blk = blockIdx.x, tid = threadIdx.x, wave = tid >> 6;
    const int gid = blk * 256 + tid;
    if (gid < NT_) aggz[gid] = 0.0f;                // zero agg
    for (int t = tid; t < 8 * N_; t += 256) ((int*)hp)[t] = 0;
    __syncthreads();

    const int g = blk >> 2, nbase = g * N_;
    int* hw_o = hp[wave * 2 + 0];
    int* hw_i = hp[wave * 2 + 1];
    const int4* s4 = (const int4*)(src + blk * (EPG_ / 4));   // 800 int4
    const int4* d4 = (const int4*)(dst + blk * (EPG_ / 4));
    for (int i = tid; i < EPG_ / 16; i += 256) {
        int4 s = s4[i]; int4 d = d4[i];
        atomicAdd(&hw_o[s.x - nbase], 1);
        atomicAdd(&hw_o[s.y - nbase], 1);
        atomicAdd(&hw_o[s.z - nbase], 1);
        atomicAdd(&hw_o[s.w - nbase], 1);
        atomicAdd(&hw_i[d.x - nbase], 1);
        atomicAdd(&hw_i[d.y - nbase], 1);
        atomicAdd(&hw_i[d.z - nbase], 1);
        atomicAdd(&hw_i[d.w - nbase], 1);
    }
    __syncthreads();
    for (int t = tid; t < N_; t += 256) {
        atomicAdd(&dego[nbase + t], hp[0][t] + hp[2][t] + hp[4][t] + hp[6][t]);
        atomicAdd(&degi[nbase + t], hp[1][t] + hp[3][t] + hp[5][t] + hp[7][t]);
    }
}

// ---------------------------------------------------------------------------
// k_scat: WIDE normed scatter-sum. Same 1024x256 shape. Each block
// redundantly computes hl = hraw * rsqrt(max(dego,1)) for its graph (400
// rsqrt — trivial), accumulates its 3200 edges into per-wave private float
// partials, merges into agg via global float atomics. Edges are L3-hot.
// ---------------------------------------------------------------------------
__global__ __launch_bounds__(256) void k_scat(const int* __restrict__ src,
                                              const int* __restrict__ dst,
                                              const float* __restrict__ hraw,
                                              const int* __restrict__ dego,
                                              float* __restrict__ agg) {
    __shared__ float hl[N_];
    __shared__ float sp[4][N_];  // per-wave private partials, 6.4 KB
    const int blk = blockIdx.x, tid = threadIdx.x, wave = tid >> 6;
    const int g = blk >> 2, nbase = g * N_;
    for (int t = tid; t < N_; t += 256)
        hl[t] = hraw[nbase + t] * (1.0f / sqrtf(fmaxf((float)dego[nbase + t], 1.0f)));
    for (int t = tid; t < 4 * N_; t += 256) ((float*)sp)[t] = 0.0f;
    __syncthreads();

    float* spw = sp[wave];
    const int4* s4 = (const int4*)(src + blk * (EPG_ / 4));
    const int4* d4 = (const int4*)(dst + blk * (EPG_ / 4));
    for (int i = tid; i < EPG_ / 16; i += 256) {
        int4 s = s4[i]; int4 d = d4[i];
        atomicAdd(&spw[d.x - nbase], hl[s.x - nbase]);
        atomicAdd(&spw[d.y - nbase], hl[s.y - nbase]);
        atomicAdd(&spw[d.z - nbase], hl[s.z - nbase]);
        atomicAdd(&spw[d.w - nbase], hl[s.w - nbase]);
    }
    __syncthreads();
    for (int t = tid; t < N_; t += 256)
        atomicAdd(&agg[nbase + t], sp[0][t] + sp[1][t] + sp[2][t] + sp[3][t]);
}

// ---------------------------------------------------------------------------
// k_top: per-graph score + top-k ONLY (256 blocks x 512 thr = 8 waves).
// score = agg * rsqrt(max(degi,1)) + b, written IN-PLACE over agg.
// Rank-select via __builtin_amdgcn_readlane with compile-time lanes: pure
// VALU broadcast (no LDS-pipe ds_bpermute like __shfl). rank_i = #{j: s_j >
// s_i or (s_j==s_i and j<i)} == lax.top_k stable-descending position.
// Complement positions from ballot masks. Wave 7 does the softmax partial.
// ---------------------------------------------------------------------------
__global__ __launch_bounds__(512) void k_top(float* __restrict__ sc,   // agg in, score out (in-place)
                                             const int* __restrict__ degi,
                                             const float* __restrict__ bp,
                                             float* __restrict__ pm,
                                             float* __restrict__ ps,
                                             int* __restrict__ sel,
                                             int* __restrict__ orow,
                                             float* __restrict__ out) {
    __shared__ float scl[N_];
    __shared__ unsigned long long bmask[7];
    const int g = blockIdx.x, tid = threadIdx.x;
    const int wave = tid >> 6, lane = tid & 63;
    const int nbase = g * N_;

    const float bb = bp[0];
    if (tid < N_) {
        float v = sc[nbase + tid] * (1.0f / sqrtf(fmaxf((float)degi[nbase + tid], 1.0f))) + bb;
        sc[nbase + tid] = v;     // in-place agg -> score (same thread, WAR-safe)
        scl[tid] = v;
    }
    __syncthreads();

    bool selb = false;
    if (tid < 448) {             // waves 0-6
        float sreg[7];
        #pragma unroll
        for (int t = 0; t < 7; ++t) {
            const int j = t * 64 + lane;
            sreg[t] = (j < N_) ? scl[j] : NEG_INF;
        }
        const float v = (tid < N_) ? scl[tid] : NEG_INF;
        int rnk = 0;
        #pragma unroll
        for (int t = 0; t < 7; ++t) {
            #pragma unroll
            for (int l2 = 0; l2 < 64; ++l2) {
                const int j = t * 64 + l2;
                if (j < N_) {    // compile-time prune (t=6, l2>=16)
                    const float u = __uint_as_float(
                        __builtin_amdgcn_readlane(__float_as_uint(sreg[t]), l2));
                    rnk += ((u > v) || (u == v && j < tid)) ? 1 : 0;
                }
            }
        }
        selb = (tid < N_) && (rnk < K_);
        if (tid < N_) sel[nbase + tid] = selb ? 1 : 0;
        if (selb) {
            orow[nbase + tid] = g * K_ + rnk;               // dis rows [0,B*K)
            out[O_PERM + g * K_ + rnk] = (float)(nbase + tid);
        }
        unsigned long long bal = __ballot(selb);
        if (lane == 0) bmask[wave] = bal;
    }
    // Wave 7: per-graph softmax partial (reads scl only).
    if (wave == 7) {
        float m = NEG_INF;
        for (int i = lane; i < N_; i += 64) m = fmaxf(m, scl[i]);
        #pragma unroll
        for (int o = 32; o > 0; o >>= 1) m = fmaxf(m, __shfl_xor(m, o, 64));
        float s = 0.0f;
        for (int i = lane; i < N_; i += 64) s += expf(scl[i] - m);
        #pragma unroll
        for (int o = 32; o > 0; o >>= 1) s += __shfl_xor(s, o, 64);
        if (lane == 0) { pm[g] = m; ps[g] = s; }
    }
    __syncthreads();

    // Complement positions from ballots: pos = tid - #selected_below
    if (tid < N_ && !selb) {
        int nsel = 0;
        #pragma unroll
        for (int w = 0; w < 7; ++w)
            if (w < wave) nsel += (int)__popcll(bmask[w]);
        nsel += (int)__popcll(bmask[wave] & ((1ull << lane) - 1ull));
        const int pos = tid - nsel;
        orow[nbase + tid] = B_ * K_ + g * NKC_ + pos;       // com rows
        out[O_PCOM + g * NKC_ + pos] = (float)(nbase + tid);
    }
}

// Combine per-graph (max,sumexp) into global (M,S)
__global__ __launch_bounds__(256) void k_soft_comb(const float* pm, const float* ps, float* red2) {
    __shared__ float rm[256], rs[256];
    int tid = threadIdx.x;
    float m = pm[tid];
    rm[tid] = m; __syncthreads();
    for (int o = 128; o > 0; o >>= 1) { if (tid < o) rm[tid] = fmaxf(rm[tid], rm[tid + o]); __syncthreads(); }
    float M = rm[0]; __syncthreads();
    rs[tid] = ps[tid] * expf(m - M); __syncthreads();
    for (int o = 128; o > 0; o >>= 1) { if (tid < o) rs[tid] += rs[tid + o]; __syncthreads(); }
    if (tid == 0) { red2[0] = M; red2[1] = rs[0]; }
}

// Edge masks: wide (3200 blocks). Edges L3-hot, sel L2-resident, nt writes.
__global__ __launch_bounds__(256) void k_mask(const int* __restrict__ src,
                                              const int* __restrict__ dst,
                                              const int* __restrict__ sel,
                                              float* __restrict__ out) {
    const int i = blockIdx.x * 256 + threadIdx.x;   // 0 .. E/4-1
    int4 s = ((const int4*)src)[i];
    int4 d = ((const int4*)dst)[i];
    int a0 = sel[s.x], a1 = sel[s.y], a2 = sel[s.z], a3 = sel[s.w];
    int b0 = sel[d.x], b1 = sel[d.y], b2 = sel[d.z], b3 = sel[d.w];
    float4 mdis, mcom;
    mdis.x = (a0 & b0) ? 1.0f : 0.0f;  mcom.x = (a0 | b0) ? 0.0f : 1.0f;
    mdis.y = (a1 & b1) ? 1.0f : 0.0f;  mcom.y = (a1 | b1) ? 0.0f : 1.0f;
    mdis.z = (a2 & b2) ? 1.0f : 0.0f;  mcom.z = (a2 | b2) ? 0.0f : 1.0f;
    mdis.w = (a3 & b3) ? 1.0f : 0.0f;  mcom.w = (a3 | b3) ? 0.0f : 1.0f;
    nt_store4(((float4*)(out + O_EDIS)) + i, mdis);
    nt_store4(((float4*)(out + O_ECOM)) + i, mcom);
}

// Gated gather: linear feat reads (L3-hot), rows scattered to orow[n]*D via
// nt stores. Softmax output fused. Grid MUST be NT_/16 blocks.
__global__ __launch_bounds__(256) void k_gather(const float* __restrict__ feat,
                                                const float* __restrict__ score,
                                                const int* __restrict__ orow,
                                                const float* __restrict__ red2,
                                                float* __restrict__ out) {
    const int gw   = (blockIdx.x * 256 + threadIdx.x) >> 6;
    const int lane = threadIdx.x & 63;
    const int n0 = gw * 4;
    const float4* fb = (const float4*)feat;
    float4 v0 = fb[(size_t)(n0    ) * 64 + lane];
    float4 v1 = fb[(size_t)(n0 + 1) * 64 + lane];
    float4 v2 = fb[(size_t)(n0 + 2) * 64 + lane];
    float4 v3 = fb[(size_t)(n0 + 3) * 64 + lane];
    float s0 = score[n0], s1 = score[n0 + 1], s2 = score[n0 + 2], s3 = score[n0 + 3];
    int   r0 = orow[n0],  r1 = orow[n0 + 1],  r2 = orow[n0 + 2],  r3 = orow[n0 + 3];
    float t0 = tanhf(s0), t1 = tanhf(s1), t2 = tanhf(s2), t3 = tanhf(s3);
    v0.x *= t0; v0.y *= t0; v0.z *= t0; v0.w *= t0;
    v1.x *= t1; v1.y *= t1; v1.z *= t1; v1.w *= t1;
    v2.x *= t2; v2.y *= t2; v2.z *= t2; v2.w *= t2;
    v3.x *= t3; v3.y *= t3; v3.z *= t3; v3.w *= t3;
    nt_store4(((float4*)(out + (size_t)r0 * D_)) + lane, v0);
    nt_store4(((float4*)(out + (size_t)r1 * D_)) + lane, v1);
    nt_store4(((float4*)(out + (size_t)r2 * D_)) + lane, v2);
    nt_store4(((float4*)(out + (size_t)r3 * D_)) + lane, v3);
    if (lane == 0) {
        float M = red2[0], S = red2[1];
        out[O_SOFT + n0    ] = expf(s0 - M) / S;
        out[O_SOFT + n0 + 1] = expf(s1 - M) / S;
        out[O_SOFT + n0 + 2] = expf(s2 - M) / S;
        out[O_SOFT + n0 + 3] = expf(s3 - M) / S;
    }
}

extern "C" void kernel_launch(void* const* d_in, const int* in_sizes, int n_in,
                              void* d_out, int out_size, void* d_ws, size_t ws_size,
                              hipStream_t stream) {
    const float* feat = (const float*)d_in[0];
    const float* W    = (const float*)d_in[1];
    const float* bp   = (const float*)d_in[2];
    const int*   src  = (const int*)d_in[3];
    const int*   dst  = (const int*)d_in[4];
    float* out = (float*)d_out;

    // Workspace layout WITH ALIASING (all reuses are across dispatch
    // boundaries, write-after-last-read — verified per phase):
    //   [0       ) dego (NT int)  -> reused as orow by k_top (dego dead after k_scat)
    //   [409600  ) degi (NT int)     (live through k_top)
    //   [819200  ) agg  (NT f32)  -> score written IN-PLACE by k_top
    //   [1228800 ) hraw (NT f32)  -> reused as sel by k_top (hraw dead after k_scat)
    //   [1638400 ) pm (B f32), ps, red2
    char* ws = (char*)d_ws;
    int*   dego  = (int*)  (ws + 0);
    int*   degi  = (int*)  (ws + 409600);
    float* agg   = (float*)(ws + 819200);    // becomes score
    float* hraw  = (float*)(ws + 1228800);   // becomes sel
    float* pm    = (float*)(ws + 1638400);
    float* ps    = (float*)(ws + 1639424);
    float* red2  = (float*)(ws + 1640448);
    int*   orow  = (int*)  (ws + 0);
    int*   sel   = (int*)  (ws + 1228800);
    float* score = agg;

    k_h        <<<NT_ / 16,     256, 0, stream>>>(feat, W, hraw, dego);     // zeroes dego+degi
    k_deg      <<<4 * B_,       256, 0, stream>>>(src, dst, dego, degi, agg); // zeroes agg
    k_scat     <<<4 * B_,       256, 0, stream>>>(src, dst, hraw, dego, agg);
    k_top      <<<B_,           512, 0, stream>>>(score, degi, bp, pm, ps, sel, orow, out);
    k_soft_comb<<<1,            256, 0, stream>>>(pm, ps, red2);
    k_mask     <<<E_ / 4 / 256, 256, 0, stream>>>(src, dst, sel, out);
    k_gather   <<<NT_ / 16,     256, 0, stream>>>(feat, score, orow, red2, out);
}

// Round 7
// 289.243 us; speedup vs baseline: 1.0165x; 1.0157x over previous
//
#include <hip/hip_runtime.h>
#include <math.h>

// Problem constants (static per reference)
#define B_    256
#define N_    400
#define D_    256
#define EPG_  12800          // N*DEG edges per graph (block-diagonal, contiguous)
#define E_    3276800        // B*EPG
#define NT_   102400         // B*N
#define K_    200            // ceil(0.5*N)
#define NKC_  200            // N-K
#define QB_   1024           // quarter-graph blocks (4 per graph)
#define EPQ_  3200           // edges per quarter-graph block

// Output flat offsets (float32 elements, in return order).
#define O_FDIS 0
#define O_FCOM 13107200      // + B*K*D
#define O_PERM 26214400      // + B*NKC*D
#define O_PCOM 26265600      // + B*K
#define O_SOFT 26316800      // + B*NKC
#define O_EDIS 26419200      // + NT
#define O_ECOM 29696000      // + E

#define NEG_INF (-3.402823466e38f)

// Native clang vector for __builtin_nontemporal_store (rejects HIP float4).
typedef float nfv4 __attribute__((ext_vector_type(4)));
static __device__ __forceinline__ void nt_store4(float4* p, float4 v) {
    nfv4 x; x.x = v.x; x.y = v.y; x.z = v.z; x.w = v.w;
    __builtin_nontemporal_store(x, (nfv4*)p);
}

// ---------------------------------------------------------------------------
// A: two independent block populations in one dispatch (overlapped streams,
// no dependency, NO zero-init needed anywhere):
//   blocks [0,6400):     hraw[n] = dot(feat[n],W)  (105 MB feat stream)
//   blocks [6400,7424):  per-quarter-graph degree histograms (26 MB edge
//                        stream) -> PARTIAL counts degp_o/degp_i[qb][N]
//                        (plain coalesced stores; no atomics, no pre-zero)
// ---------------------------------------------------------------------------
__global__ __launch_bounds__(256) void k_A(const float* __restrict__ feat,
                                           const float* __restrict__ W,
                                           const int* __restrict__ src,
                                           const int* __restrict__ dst,
                                           float* __restrict__ hraw,
                                           int* __restrict__ degp_o,
                                           int* __restrict__ degp_i) {
    const int bid = blockIdx.x, tid = threadIdx.x;
    if (bid < NT_ / 16) {
        // --- k_h population
        const int gw   = (bid * 256 + tid) >> 6;
        const int lane = tid & 63;
        const float4 w4 = ((const float4*)W)[lane];
        const int r0 = gw * 4;
        const float4* fb = (const float4*)feat;
        float4 a0 = fb[(size_t)(r0    ) * 64 + lane];
        float4 a1 = fb[(size_t)(r0 + 1) * 64 + lane];
        float4 a2 = fb[(size_t)(r0 + 2) * 64 + lane];
        float4 a3 = fb[(size_t)(r0 + 3) * 64 + lane];
        float d0 = a0.x*w4.x + a0.y*w4.y + a0.z*w4.z + a0.w*w4.w;
        float d1 = a1.x*w4.x + a1.y*w4.y + a1.z*w4.z + a1.w*w4.w;
        float d2 = a2.x*w4.x + a2.y*w4.y + a2.z*w4.z + a2.w*w4.w;
        float d3 = a3.x*w4.x + a3.y*w4.y + a3.z*w4.z + a3.w*w4.w;
        #pragma unroll
        for (int off = 32; off > 0; off >>= 1) {
            d0 += __shfl_down(d0, off, 64);
            d1 += __shfl_down(d1, off, 64);
            d2 += __shfl_down(d2, off, 64);
            d3 += __shfl_down(d3, off, 64);
        }
        if (lane == 0) {
            hraw[r0    ] = d0;
            hraw[r0 + 1] = d1;
            hraw[r0 + 2] = d2;
            hraw[r0 + 3] = d3;
        }
    } else {
        // --- degree-histogram population (per-wave private LDS hists)
        __shared__ int hp[8][N_];    // 12.8 KB
        const int qb = bid - NT_ / 16;          // [0, QB_)
        const int wave = tid >> 6;
        const int nbase = (qb >> 2) * N_;
        for (int t = tid; t < 8 * N_; t += 256) ((int*)hp)[t] = 0;
        __syncthreads();
        int* hw_o = hp[wave * 2 + 0];
        int* hw_i = hp[wave * 2 + 1];
        const int4* s4 = (const int4*)(src + qb * EPQ_);   // 800 int4
        const int4* d4 = (const int4*)(dst + qb * EPQ_);
        for (int i = tid; i < EPQ_ / 4; i += 256) {
            int4 s = s4[i]; int4 d = d4[i];
            atomicAdd(&hw_o[s.x - nbase], 1);
            atomicAdd(&hw_o[s.y - nbase], 1);
            atomicAdd(&hw_o[s.z - nbase], 1);
            atomicAdd(&hw_o[s.w - nbase], 1);
            atomicAdd(&hw_i[d.x - nbase], 1);
            atomicAdd(&hw_i[d.y - nbase], 1);
            atomicAdd(&hw_i[d.z - nbase], 1);
            atomicAdd(&hw_i[d.w - nbase], 1);
        }
        __syncthreads();
        for (int t = tid; t < N_; t += 256) {
            degp_o[qb * N_ + t] = hp[0][t] + hp[2][t] + hp[4][t] + hp[6][t];
            degp_i[qb * N_ + t] = hp[1][t] + hp[3][t] + hp[5][t] + hp[7][t];
        }
    }
}

// ---------------------------------------------------------------------------
// B: scatter partials. 1024 blocks (quarter-graph each). hl computed from
// the 4 degree partials (16 KB/graph, L2-hot); per-wave private float
// partials in LDS; PARTIAL result aggp[qb][N] via plain stores. Edges L3-hot.
// ---------------------------------------------------------------------------
__global__ __launch_bounds__(256) void k_B(const int* __restrict__ src,
                                           const int* __restrict__ dst,
                                           const float* __restrict__ hraw,
                                           const int* __restrict__ degp_o,
                                           float* __restrict__ aggp) {
    __shared__ float hl[N_];
    __shared__ float sp[4][N_];  // 6.4 KB
    const int qb = blockIdx.x, tid = threadIdx.x, wave = tid >> 6;
    const int g = qb >> 2, nbase = g * N_, g4 = g * 4;
    for (int t = tid; t < N_; t += 256) {
        const int dsum = degp_o[(g4 + 0) * N_ + t] + degp_o[(g4 + 1) * N_ + t]
                       + degp_o[(g4 + 2) * N_ + t] + degp_o[(g4 + 3) * N_ + t];
        hl[t] = hraw[nbase + t] * (1.0f / sqrtf(fmaxf((float)dsum, 1.0f)));
    }
    for (int t = tid; t < 4 * N_; t += 256) ((float*)sp)[t] = 0.0f;
    __syncthreads();

    float* spw = sp[wave];
    const int4* s4 = (const int4*)(src + qb * EPQ_);
    const int4* d4 = (const int4*)(dst + qb * EPQ_);
    for (int i = tid; i < EPQ_ / 4; i += 256) {
        int4 s = s4[i]; int4 d = d4[i];
        atomicAdd(&spw[d.x - nbase], hl[s.x - nbase]);
        atomicAdd(&spw[d.y - nbase], hl[s.y - nbase]);
        atomicAdd(&spw[d.z - nbase], hl[s.z - nbase]);
        atomicAdd(&spw[d.w - nbase], hl[s.w - nbase]);
    }
    __syncthreads();
    for (int t = tid; t < N_; t += 256)
        aggp[qb * N_ + t] = sp[0][t] + sp[1][t] + sp[2][t] + sp[3][t];
}

// ---------------------------------------------------------------------------
// C: per-graph score + top-k. 256 blocks x 512 thr. score = (Σ4 aggp) *
// rsqrt(max(Σ4 degp_i,1)) + b. Rank-select via readlane (pure VALU, no
// LDS-pipe); rank == lax.top_k stable-descending position. Complement via
// ballots. Wave 7 does the softmax partial.
// ---------------------------------------------------------------------------
__global__ __launch_bounds__(512) void k_C(const float* __restrict__ aggp,
                                           const int* __restrict__ degp_i,
                                           const float* __restrict__ bp,
                                           float* __restrict__ score,
                                           float* __restrict__ pm,
                                           float* __restrict__ ps,
                                           int* __restrict__ sel,
                                           int* __restrict__ orow,
                                           float* __restrict__ out) {
    __shared__ float scl[N_];
    __shared__ unsigned long long bmask[7];
    const int g = blockIdx.x, tid = threadIdx.x;
    const int wave = tid >> 6, lane = tid & 63;
    const int nbase = g * N_, g4 = g * 4;

    const float bb = bp[0];
    if (tid < N_) {
        const float a = aggp[(g4 + 0) * N_ + tid] + aggp[(g4 + 1) * N_ + tid]
                      + aggp[(g4 + 2) * N_ + tid] + aggp[(g4 + 3) * N_ + tid];
        const int dsum = degp_i[(g4 + 0) * N_ + tid] + degp_i[(g4 + 1) * N_ + tid]
                       + degp_i[(g4 + 2) * N_ + tid] + degp_i[(g4 + 3) * N_ + tid];
        const float v = a * (1.0f / sqrtf(fmaxf((float)dsum, 1.0f))) + bb;
        score[nbase + tid] = v;
        scl[tid] = v;
    }
    __syncthreads();

    bool selb = false;
    if (tid < 448) {             // waves 0-6
        float sreg[7];
        #pragma unroll
        for (int t = 0; t < 7; ++t) {
            const int j = t * 64 + lane;
            sreg[t] = (j < N_) ? scl[j] : NEG_INF;
        }
        const float v = (tid < N_) ? scl[tid] : NEG_INF;
        int rnk = 0;
        #pragma unroll
        for (int t = 0; t < 7; ++t) {
            #pragma unroll
            for (int l2 = 0; l2 < 64; ++l2) {
                const int j = t * 64 + l2;
                if (j < N_) {    // compile-time prune (t=6, l2>=16)
                    const float u = __uint_as_float(
                        __builtin_amdgcn_readlane(__float_as_uint(sreg[t]), l2));
                    rnk += ((u > v) || (u == v && j < tid)) ? 1 : 0;
                }
            }
        }
        selb = (tid < N_) && (rnk < K_);
        if (tid < N_) sel[nbase + tid] = selb ? 1 : 0;
        if (selb) {
            orow[nbase + tid] = g * K_ + rnk;               // dis rows [0,B*K)
            out[O_PERM + g * K_ + rnk] = (float)(nbase + tid);
        }
        unsigned long long bal = __ballot(selb);
        if (lane == 0) bmask[wave] = bal;
    }
    // Wave 7: per-graph softmax partial (reads scl only).
    if (wave == 7) {
        float m = NEG_INF;
        for (int i = lane; i < N_; i += 64) m = fmaxf(m, scl[i]);
        #pragma unroll
        for (int o = 32; o > 0; o >>= 1) m = fmaxf(m, __shfl_xor(m, o, 64));
        float s = 0.0f;
        for (int i = lane; i < N_; i += 64) s += expf(scl[i] - m);
        #pragma unroll
        for (int o = 32; o > 0; o >>= 1) s += __shfl_xor(s, o, 64);
        if (lane == 0) { pm[g] = m; ps[g] = s; }
    }
    __syncthreads();

    // Complement positions from ballots: pos = tid - #selected_below
    if (tid < N_ && !selb) {
        int nsel = 0;
        #pragma unroll
        for (int w = 0; w < 7; ++w)
            if (w < wave) nsel += (int)__popcll(bmask[w]);
        nsel += (int)__popcll(bmask[wave] & ((1ull << lane) - 1ull));
        const int pos = tid - nsel;
        orow[nbase + tid] = B_ * K_ + g * NKC_ + pos;       // com rows
        out[O_PCOM + g * NKC_ + pos] = (float)(nbase + tid);
    }
}

// ---------------------------------------------------------------------------
// D: two independent block populations in one dispatch:
//   blocks [0,6400):      gated gather (feat L3-hot, nt row stores) with
//                         per-block softmax combine from pm/ps (2 KB, L2-hot)
//                         and fused softmax output
//   blocks [6400,9600):   edge masks (edges L3-hot, sel L2-hot, nt stores)
// ---------------------------------------------------------------------------
__global__ __launch_bounds__(256) void k_D(const float* __restrict__ feat,
                                           const float* __restrict__ score,
                                           const int* __restrict__ orow,
                                           const float* __restrict__ pm,
                                           const float* __restrict__ ps,
                                           const int* __restrict__ src,
                                           const int* __restrict__ dst,
                                           const int* __restrict__ sel,
                                           float* __restrict__ out) {
    const int bid = blockIdx.x, tid = threadIdx.x;
    if (bid < NT_ / 16) {
        // --- gather population: combine (M,S) from the 256 per-graph partials
        __shared__ float sm[4], ss[4];
        const int lane = tid & 63, wv = tid >> 6;
        float m = pm[tid], s = ps[tid];
        #pragma unroll
        for (int o = 32; o > 0; o >>= 1) {
            float mo = __shfl_xor(m, o, 64);
            float so = __shfl_xor(s, o, 64);
            float M2 = fmaxf(m, mo);
            s = s * expf(m - M2) + so * expf(mo - M2);
            m = M2;
        }
        if (lane == 0) { sm[wv] = m; ss[wv] = s; }
        __syncthreads();
        const float M = fmaxf(fmaxf(sm[0], sm[1]), fmaxf(sm[2], sm[3]));
        const float S = ss[0] * expf(sm[0] - M) + ss[1] * expf(sm[1] - M)
                      + ss[2] * expf(sm[2] - M) + ss[3] * expf(sm[3] - M);

        const int gw = (bid * 256 + tid) >> 6;
        const int n0 = gw * 4;
        const float4* fb = (const float4*)feat;
        float4 v0 = fb[(size_t)(n0    ) * 64 + lane];
        float4 v1 = fb[(size_t)(n0 + 1) * 64 + lane];
        float4 v2 = fb[(size_t)(n0 + 2) * 64 + lane];
        float4 v3 = fb[(size_t)(n0 + 3) * 64 + lane];
        float s0 = score[n0], s1 = score[n0 + 1], s2 = score[n0 + 2], s3 = score[n0 + 3];
        int   r0 = orow[n0],  r1 = orow[n0 + 1],  r2 = orow[n0 + 2],  r3 = orow[n0 + 3];
        float t0 = tanhf(s0), t1 = tanhf(s1), t2 = tanhf(s2), t3 = tanhf(s3);
        v0.x *= t0; v0.y *= t0; v0.z *= t0; v0.w *= t0;
        v1.x *= t1; v1.y *= t1; v1.z *= t1; v1.w *= t1;
        v2.x *= t2; v2.y *= t2; v2.z *= t2; v2.w *= t2;
        v3.x *= t3; v3.y *= t3; v3.z *= t3; v3.w *= t3;
        nt_store4(((float4*)(out + (size_t)r0 * D_)) + lane, v0);
        nt_store4(((float4*)(out + (size_t)r1 * D_)) + lane, v1);
        nt_store4(((float4*)(out + (size_t)r2 * D_)) + lane, v2);
        nt_store4(((float4*)(out + (size_t)r3 * D_)) + lane, v3);
        if (lane == 0) {
            out[O_SOFT + n0    ] = expf(s0 - M) / S;
            out[O_SOFT + n0 + 1] = expf(s1 - M) / S;
            out[O_SOFT + n0 + 2] = expf(s2 - M) / S;
            out[O_SOFT + n0 + 3] = expf(s3 - M) / S;
        }
    } else {
        // --- mask population
        const int i = (bid - NT_ / 16) * 256 + tid;   // 0 .. E/4-1
        int4 s = ((const int4*)src)[i];
        int4 d = ((const int4*)dst)[i];
        int a0 = sel[s.x], a1 = sel[s.y], a2 = sel[s.z], a3 = sel[s.w];
        int b0 = sel[d.x], b1 = sel[d.y], b2 = sel[d.z], b3 = sel[d.w];
        float4 mdis, mcom;
        mdis.x = (a0 & b0) ? 1.0f : 0.0f;  mcom.x = (a0 | b0) ? 0.0f : 1.0f;
        mdis.y = (a1 & b1) ? 1.0f : 0.0f;  mcom.y = (a1 | b1) ? 0.0f : 1.0f;
        mdis.z = (a2 & b2) ? 1.0f : 0.0f;  mcom.z = (a2 | b2) ? 0.0f : 1.0f;
        mdis.w = (a3 & b3) ? 1.0f : 0.0f;  mcom.w = (a3 | b3) ? 0.0f : 1.0f;
        nt_store4(((float4*)(out + O_EDIS)) + i, mdis);
        nt_store4(((float4*)(out + O_ECOM)) + i, mcom);
    }
}

extern "C" void kernel_launch(void* const* d_in, const int* in_sizes, int n_in,
                              void* d_out, int out_size, void* d_ws, size_t ws_size,
                              hipStream_t stream) {
    const float* feat = (const float*)d_in[0];
    const float* W    = (const float*)d_in[1];
    const float* bp   = (const float*)d_in[2];
    const int*   src  = (const int*)d_in[3];
    const int*   dst  = (const int*)d_in[4];
    float* out = (float*)d_out;

    // Workspace (no aliasing, no zero-init required anywhere):
    char* ws = (char*)d_ws;
    float* hraw   = (float*)(ws + 0);          // NT floats        (400 KB)
    int*   degp_o = (int*)  (ws + 409600);     // QB*N ints        (1.64 MB)
    int*   degp_i = (int*)  (ws + 2048000);    // QB*N ints        (1.64 MB)
    float* aggp   = (float*)(ws + 3686400);    // QB*N floats      (1.64 MB)
    float* score  = (float*)(ws + 5324800);    // NT floats
    int*   sel    = (int*)  (ws + 5734400);    // NT ints
    int*   orow   = (int*)  (ws + 6144000);    // NT ints
    float* pm     = (float*)(ws + 6553600);    // B floats
    float* ps     = (float*)(ws + 6554624);    // B floats

    k_A<<<NT_ / 16 + QB_,  256, 0, stream>>>(feat, W, src, dst, hraw, degp_o, degp_i);
    k_B<<<QB_,             256, 0, stream>>>(src, dst, hraw, degp_o, aggp);
    k_C<<<B_,              512, 0, stream>>>(aggp, degp_i, bp, score, pm, ps, sel, orow, out);
    k_D<<<NT_ / 16 + E_ / 4 / 256, 256, 0, stream>>>(feat, score, orow, pm, ps,
                                                     src, dst, sel, out);
}